// Round 1
// baseline (748.150 us; speedup 1.0000x reference)
//
#include <hip/hip_runtime.h>
#include <stdint.h>

typedef __attribute__((ext_vector_type(8))) short short8;
typedef __attribute__((ext_vector_type(4))) float floatx4;

__device__ __forceinline__ unsigned short f2bf(float f) {
    unsigned u = __float_as_uint(f);
    u += 0x7FFFu + ((u >> 16) & 1u);
    return (unsigned short)(u >> 16);
}

// C[M,N] = bf16(X[M,1024]) @ bf16(W[1024,N]) + bias, output bf16.
// TRS=false: out[m*N+n]; TRS=true: out[n*M+m] (for V^T).
template<int NCB, bool TRS>
__global__ __launch_bounds__(256)
void gemm_qkv(const float* __restrict__ X, const float* __restrict__ W,
              const float* __restrict__ bias, unsigned short* __restrict__ out,
              int M, int N)
{
    constexpr int NT = 16 * NCB;
    __shared__ unsigned short Ax[64 * 40];   // 64 rows x 32 k, stride 40
    __shared__ unsigned short Wt[NT * 40];   // NT cols x 32 k (transposed), stride 40
    const int tid = threadIdx.x;
    const int wave = tid >> 6, lane = tid & 63;
    const int quad = lane >> 4, l16 = lane & 15;
    const int m0 = blockIdx.x * 64, n0 = blockIdx.y * NT;

    floatx4 acc[NCB];
#pragma unroll
    for (int i = 0; i < NCB; i++) acc[i] = (floatx4)0.f;

    for (int e0 = 0; e0 < 1024; e0 += 32) {
        // stage X tile 64x32 -> bf16 LDS
        {
            const int r = tid >> 2, c = (tid & 3) * 8;
            const float* src = X + (size_t)(m0 + r) * 1024 + e0 + c;
            unsigned short t[8];
#pragma unroll
            for (int i = 0; i < 8; i++) t[i] = f2bf(src[i]);
            uint4 pk;
            pk.x = t[0] | ((unsigned)t[1] << 16);
            pk.y = t[2] | ((unsigned)t[3] << 16);
            pk.z = t[4] | ((unsigned)t[5] << 16);
            pk.w = t[6] | ((unsigned)t[7] << 16);
            *(uint4*)&Ax[r * 40 + c] = pk;
        }
        // stage W tile 32xNT transposed -> bf16 LDS
        for (int base = tid * 8; base < 32 * NT; base += 256 * 8) {
            const int k = base / NT, n = base % NT;
            const float* src = W + (size_t)(e0 + k) * N + n0 + n;
#pragma unroll
            for (int i = 0; i < 8; i++) Wt[(n + i) * 40 + k] = f2bf(src[i]);
        }
        __syncthreads();
        short8 a = *(const short8*)&Ax[(wave * 16 + l16) * 40 + quad * 8];
#pragma unroll
        for (int cb = 0; cb < NCB; cb++) {
            short8 bfrag = *(const short8*)&Wt[(cb * 16 + l16) * 40 + quad * 8];
            acc[cb] = __builtin_amdgcn_mfma_f32_16x16x32_bf16(a, bfrag, acc[cb], 0, 0, 0);
        }
        __syncthreads();
    }

#pragma unroll
    for (int cb = 0; cb < NCB; cb++) {
        const float bn = bias[n0 + cb * 16 + l16];
        if (TRS) {
            // rows m = m0 + wave*16 + quad*4 + reg are consecutive -> pack 4 bf16
            unsigned short t[4];
#pragma unroll
            for (int r = 0; r < 4; r++) t[r] = f2bf(acc[cb][r] + bn);
            uint2 pv;
            pv.x = t[0] | ((unsigned)t[1] << 16);
            pv.y = t[2] | ((unsigned)t[3] << 16);
            *(uint2*)&out[(size_t)(n0 + cb * 16 + l16) * M + m0 + wave * 16 + quad * 4] = pv;
        } else {
#pragma unroll
            for (int r = 0; r < 4; r++)
                out[(size_t)(m0 + wave * 16 + quad * 4 + r) * N + n0 + cb * 16 + l16] =
                    f2bf(acc[cb][r] + bn);
        }
    }
}

// Attention: per block: one batch b, 64 q-rows, half of DV (512 cols).
// 8 waves; per 32-key step: each wave computes one 16x16 S tile (rb=wave>>1, kb=wave&1),
// exp -> P in LDS; then PV: each wave owns 64 dv cols (4 col-tiles), 16 MFMAs.
// Unnormalized accumulation; divide by l at the end (scores are O(1), no overflow).
__global__ __launch_bounds__(512, 4)
void attn_fused(const unsigned short* __restrict__ Qb,  // 16384 x 64 bf16
                const unsigned short* __restrict__ Kb,  // 16384 x 64 bf16
                const unsigned short* __restrict__ Vt,  // 1024 x 16384 bf16 (dv, bs)
                const float* __restrict__ maskx,        // 4 x 4096
                float* __restrict__ out)                // 4 x 4096 x 1024
{
    __shared__ unsigned short Qs[64 * 72];  // 64 q x 64 d, stride 72
    __shared__ unsigned short Ps[64 * 40];  // 64 q x 32 k, stride 40
    __shared__ float Ls[64];

    const int tid = threadIdx.x;
    const int wave = tid >> 6, lane = tid & 63;
    const int quad = lane >> 4, l16 = lane & 15;
    const int bid = blockIdx.x;
    const int dvh = bid & 1;
    const int b = (bid >> 1) & 3;
    const int qt = 63 - (bid >> 3);          // heavy tiles first
    const int q0 = qt * 64;                  // within batch
    const int gq0 = b * 4096 + q0;

    if (tid < 64) Ls[tid] = 0.f;
    {   // stage Q tile 64x64 bf16
        const int r = tid >> 3, c = (tid & 7) * 8;
        uint4 v = *(const uint4*)&Qb[(size_t)(gq0 + r) * 64 + c];
        *(uint4*)&Qs[r * 72 + c] = v;
    }
    __syncthreads();

    const int rb = wave >> 1;   // S-phase row block 0..3
    const int kb = wave & 1;    // S-phase key block 0..1
    bool pq[4];
#pragma unroll
    for (int r = 0; r < 4; r++)
        pq[r] = maskx[b * 4096 + q0 + rb * 16 + quad * 4 + r] < -1e30f;

    const short8 qa0 = *(const short8*)&Qs[(rb * 16 + l16) * 72 + quad * 8];
    const short8 qa1 = *(const short8*)&Qs[(rb * 16 + l16) * 72 + 32 + quad * 8];

    floatx4 acc[4][4];
#pragma unroll
    for (int i = 0; i < 4; i++)
#pragma unroll
        for (int j = 0; j < 4; j++) acc[i][j] = (floatx4)0.f;
    float lacc[4] = {0.f, 0.f, 0.f, 0.f};

    const int niter = 2 * qt + 2;
    const float scale = 0.125f;
    const int dv0 = dvh * 512 + wave * 64;

    for (int kt = 0; kt < niter; kt++) {
        const int k0 = kt * 32;
        const int kg = k0 + kb * 16 + l16;   // this lane's key (within batch)
        // S = Q K^T for one 16x16 tile
        floatx4 s = (floatx4)0.f;
        const unsigned short* krow = &Kb[(size_t)(b * 4096 + kg) * 64];
        const short8 kb0 = *(const short8*)&krow[quad * 8];
        const short8 kb1 = *(const short8*)&krow[32 + quad * 8];
        s = __builtin_amdgcn_mfma_f32_16x16x32_bf16(qa0, kb0, s, 0, 0, 0);
        s = __builtin_amdgcn_mfma_f32_16x16x32_bf16(qa1, kb1, s, 0, 0, 0);
        const bool pk = maskx[b * 4096 + kg] < -1e30f;
        unsigned short pbits[4];
#pragma unroll
        for (int r = 0; r < 4; r++) {
            const int qrow = q0 + rb * 16 + quad * 4 + r;
            float p = 0.f;
            if (kg <= qrow && pk == pq[r]) p = __expf(s[r] * scale);
            lacc[r] += p;
            pbits[r] = f2bf(p);
        }
        __syncthreads();   // previous PV done reading Ps
#pragma unroll
        for (int r = 0; r < 4; r++)
            Ps[(rb * 16 + quad * 4 + r) * 40 + kb * 16 + l16] = pbits[r];
        __syncthreads();
        // PV: acc[rb2][cb] += P[rb2] @ V^T
        short8 pa[4];
#pragma unroll
        for (int r2 = 0; r2 < 4; r2++)
            pa[r2] = *(const short8*)&Ps[(r2 * 16 + l16) * 40 + quad * 8];
#pragma unroll
        for (int cb = 0; cb < 4; cb++) {
            const short8 vb = *(const short8*)&Vt[(size_t)(dv0 + cb * 16 + l16) * 16384
                                                 + b * 4096 + k0 + quad * 8];
#pragma unroll
            for (int r2 = 0; r2 < 4; r2++)
                acc[r2][cb] = __builtin_amdgcn_mfma_f32_16x16x32_bf16(pa[r2], vb, acc[r2][cb], 0, 0, 0);
        }
    }

    // reduce row sums l across the 16 lanes of each quad-group, combine via LDS
#pragma unroll
    for (int r = 0; r < 4; r++) {
        float v = lacc[r];
        v += __shfl_xor(v, 1);
        v += __shfl_xor(v, 2);
        v += __shfl_xor(v, 4);
        v += __shfl_xor(v, 8);
        if (l16 == 0) atomicAdd(&Ls[rb * 16 + quad * 4 + r], v);
    }
    __syncthreads();

#pragma unroll
    for (int r2 = 0; r2 < 4; r2++) {
#pragma unroll
        for (int r = 0; r < 4; r++) {
            const int qrow = q0 + r2 * 16 + quad * 4 + r;
            const float inv = 1.f / Ls[r2 * 16 + quad * 4 + r];
#pragma unroll
            for (int cb = 0; cb < 4; cb++)
                out[(size_t)(b * 4096 + qrow) * 1024 + dv0 + cb * 16 + l16] = acc[r2][cb][r] * inv;
        }
    }
}

extern "C" void kernel_launch(void* const* d_in, const int* in_sizes, int n_in,
                              void* d_out, int out_size, void* d_ws, size_t ws_size,
                              hipStream_t stream) {
    const float* x  = (const float*)d_in[0];
    const float* Wq = (const float*)d_in[1];
    const float* bq = (const float*)d_in[2];
    const float* Wk = (const float*)d_in[3];
    const float* bk = (const float*)d_in[4];
    const float* Wv = (const float*)d_in[5];
    const float* bv = (const float*)d_in[6];
    const float* mk = (const float*)d_in[7];
    float* out = (float*)d_out;

    const int M = 4 * 4096;  // 16384
    unsigned short* Qb = (unsigned short*)d_ws;
    unsigned short* Kb = Qb + (size_t)M * 64;
    unsigned short* Vt = Kb + (size_t)M * 64;   // 1024 x 16384

    gemm_qkv<4, false><<<dim3(M / 64, 1), 256, 0, stream>>>(x, Wq, bq, Qb, M, 64);
    gemm_qkv<4, false><<<dim3(M / 64, 1), 256, 0, stream>>>(x, Wk, bk, Kb, M, 64);
    gemm_qkv<8, true ><<<dim3(M / 64, 8), 256, 0, stream>>>(x, Wv, bv, Vt, M, 1024);
    attn_fused<<<dim3(4 * 64 * 2), 512, 0, stream>>>(Qb, Kb, Vt, mk, out);
}

// Round 2
// 477.980 us; speedup vs baseline: 1.5652x; 1.5652x over previous
//
#include <hip/hip_runtime.h>
#include <stdint.h>

typedef __attribute__((ext_vector_type(8))) short short8;
typedef __attribute__((ext_vector_type(4))) float floatx4;

__device__ __forceinline__ unsigned short f2bf(float f) {
    unsigned u = __float_as_uint(f);
    u += 0x7FFFu + ((u >> 16) & 1u);
    return (unsigned short)(u >> 16);
}

__device__ __forceinline__ void gload_lds16(const void* g, void* l) {
    __builtin_amdgcn_global_load_lds(
        (const __attribute__((address_space(1))) unsigned int*)g,
        (__attribute__((address_space(3))) unsigned int*)l, 16, 0, 0);
}

// ---- prep: X fp32 -> bf16 (same layout) ----
__global__ __launch_bounds__(256)
void conv_x(const float* __restrict__ x, unsigned short* __restrict__ xb) {
    const size_t total = (size_t)16384 * 1024;
    for (size_t i = ((size_t)blockIdx.x * 256 + threadIdx.x) * 8; i < total;
         i += (size_t)2048 * 256 * 8) {
        float4 a = *(const float4*)&x[i];
        float4 b = *(const float4*)&x[i + 4];
        uint4 o;
        o.x = f2bf(a.x) | ((unsigned)f2bf(a.y) << 16);
        o.y = f2bf(a.z) | ((unsigned)f2bf(a.w) << 16);
        o.z = f2bf(b.x) | ((unsigned)f2bf(b.y) << 16);
        o.w = f2bf(b.z) | ((unsigned)f2bf(b.w) << 16);
        *(uint4*)&xb[i] = o;
    }
}

// ---- prep: W [1024][N] fp32 -> Wt [N][1024] bf16 (LDS-tiled transpose) ----
__global__ __launch_bounds__(256)
void transpose_w(const float* __restrict__ src, unsigned short* __restrict__ dst, int N) {
    __shared__ float T[64][65];
    const int t = threadIdx.x;
    const int k0 = blockIdx.x * 64, n0 = blockIdx.y * 64;
    const int r = t >> 4, c4 = (t & 15) * 4;
#pragma unroll
    for (int i = 0; i < 4; i++) {
        float4 v = *(const float4*)&src[(size_t)(k0 + r + 16 * i) * N + n0 + c4];
        T[r + 16 * i][c4] = v.x; T[r + 16 * i][c4 + 1] = v.y;
        T[r + 16 * i][c4 + 2] = v.z; T[r + 16 * i][c4 + 3] = v.w;
    }
    __syncthreads();
#pragma unroll
    for (int i = 0; i < 4; i++) {
        const int n = n0 + r + 16 * i;
        unsigned short b0 = f2bf(T[c4 + 0][r + 16 * i]);
        unsigned short b1 = f2bf(T[c4 + 1][r + 16 * i]);
        unsigned short b2 = f2bf(T[c4 + 2][r + 16 * i]);
        unsigned short b3 = f2bf(T[c4 + 3][r + 16 * i]);
        uint2 pv;
        pv.x = b0 | ((unsigned)b1 << 16);
        pv.y = b2 | ((unsigned)b3 << 16);
        *(uint2*)&dst[(size_t)n * 1024 + k0 + c4] = pv;
    }
}

__global__ __launch_bounds__(128)
void pack_bias(const float* __restrict__ bq, const float* __restrict__ bk,
               float* __restrict__ bqk) {
    const int t = threadIdx.x;
    bqk[t] = (t < 64) ? bq[t] : bk[t - 64];
}

// ---- m97-style 128x128 bf16 GEMM: C = A[M][1024] @ Bt[N][1024]^T + bias ----
// TRS=false: out[m*N+n] bf16; TRS=true: out[n*M+m] bf16.
template<bool TRS>
__global__ __launch_bounds__(256)
void gemm_bf16(const unsigned short* __restrict__ A,
               const unsigned short* __restrict__ Bt,
               const float* __restrict__ bias,
               unsigned short* __restrict__ out, int M, int N)
{
    __shared__ unsigned short As[128 * 32];   // [row][k] contiguous, 8 KB
    __shared__ unsigned short Bs[128 * 32];
    const int tid = threadIdx.x;
    const int w = tid >> 6, l = tid & 63;
    const int quad = l >> 4, l16 = l & 15;
    const int wr = w >> 1, wc = w & 1;
    const int m0 = blockIdx.x * 128, n0 = blockIdx.y * 128;

    // staging addresses: chunk = 16 rows x 32 k = 1 KB per wave-issue
    const int lr = l >> 2, lk = (l & 3) * 8;
    const unsigned short* Ag0 = A + (size_t)(m0 + w * 16 + lr) * 1024 + lk;
    const unsigned short* Ag1 = Ag0 + (size_t)64 * 1024;
    const unsigned short* Bg0 = Bt + (size_t)(n0 + w * 16 + lr) * 1024 + lk;
    const unsigned short* Bg1 = Bg0 + (size_t)64 * 1024;
    unsigned short* Al0 = &As[w * 512 + l * 8];
    unsigned short* Bl0 = &Bs[w * 512 + l * 8];

    floatx4 acc[4][4];
#pragma unroll
    for (int i = 0; i < 4; i++)
#pragma unroll
        for (int j = 0; j < 4; j++) acc[i][j] = (floatx4)0.f;

    for (int e0 = 0; e0 < 1024; e0 += 32) {
        gload_lds16(Ag0 + e0, Al0);
        gload_lds16(Ag1 + e0, Al0 + 2048);
        gload_lds16(Bg0 + e0, Bl0);
        gload_lds16(Bg1 + e0, Bl0 + 2048);
        __syncthreads();
        short8 af[4], bf[4];
#pragma unroll
        for (int i = 0; i < 4; i++)
            af[i] = *(const short8*)&As[(wr * 64 + i * 16 + l16) * 32 + quad * 8];
#pragma unroll
        for (int j = 0; j < 4; j++)
            bf[j] = *(const short8*)&Bs[(wc * 64 + j * 16 + l16) * 32 + quad * 8];
#pragma unroll
        for (int i = 0; i < 4; i++)
#pragma unroll
            for (int j = 0; j < 4; j++)
                acc[i][j] = __builtin_amdgcn_mfma_f32_16x16x32_bf16(af[i], bf[j], acc[i][j], 0, 0, 0);
        __syncthreads();
    }

#pragma unroll
    for (int j = 0; j < 4; j++) {
        const int n = n0 + wc * 64 + j * 16 + l16;
        const float bn = bias[n];
#pragma unroll
        for (int i = 0; i < 4; i++) {
            const int mb = m0 + wr * 64 + i * 16 + quad * 4;
            if (TRS) {
                unsigned short t[4];
#pragma unroll
                for (int r = 0; r < 4; r++) t[r] = f2bf(acc[i][j][r] + bn);
                uint2 pv;
                pv.x = t[0] | ((unsigned)t[1] << 16);
                pv.y = t[2] | ((unsigned)t[3] << 16);
                *(uint2*)&out[(size_t)n * M + mb] = pv;
            } else {
#pragma unroll
                for (int r = 0; r < 4; r++)
                    out[(size_t)(mb + r) * N + n] = f2bf(acc[i][j][r] + bn);
            }
        }
    }
}

// ---- attention (unchanged structure; Q/K from combined QK[s][128] buffer) ----
__global__ __launch_bounds__(512, 4)
void attn_fused(const unsigned short* __restrict__ QKb, // 16384 x 128 bf16 (Q|K)
                const unsigned short* __restrict__ Vt,  // 1024 x 16384 bf16 (dv, bs)
                const float* __restrict__ maskx,        // 4 x 4096
                float* __restrict__ out)                // 4 x 4096 x 1024
{
    __shared__ unsigned short Qs[64 * 72];
    __shared__ unsigned short Ps[64 * 40];
    __shared__ float Ls[64];

    const int tid = threadIdx.x;
    const int wave = tid >> 6, lane = tid & 63;
    const int quad = lane >> 4, l16 = lane & 15;
    const int bid = blockIdx.x;
    const int dvh = bid & 1;
    const int b = (bid >> 1) & 3;
    const int qt = 63 - (bid >> 3);
    const int q0 = qt * 64;
    const int gq0 = b * 4096 + q0;

    if (tid < 64) Ls[tid] = 0.f;
    {
        const int r = tid >> 3, c = (tid & 7) * 8;
        uint4 v = *(const uint4*)&QKb[(size_t)(gq0 + r) * 128 + c];
        *(uint4*)&Qs[r * 72 + c] = v;
    }
    __syncthreads();

    const int rb = wave >> 1;
    const int kb = wave & 1;
    bool pq[4];
#pragma unroll
    for (int r = 0; r < 4; r++)
        pq[r] = maskx[b * 4096 + q0 + rb * 16 + quad * 4 + r] < -1e30f;

    const short8 qa0 = *(const short8*)&Qs[(rb * 16 + l16) * 72 + quad * 8];
    const short8 qa1 = *(const short8*)&Qs[(rb * 16 + l16) * 72 + 32 + quad * 8];

    floatx4 acc[4][4];
#pragma unroll
    for (int i = 0; i < 4; i++)
#pragma unroll
        for (int j = 0; j < 4; j++) acc[i][j] = (floatx4)0.f;
    float lacc[4] = {0.f, 0.f, 0.f, 0.f};

    const int niter = 2 * qt + 2;
    const float scale = 0.125f;
    const int dv0 = dvh * 512 + wave * 64;

    for (int kt = 0; kt < niter; kt++) {
        const int k0 = kt * 32;
        const int kg = k0 + kb * 16 + l16;
        floatx4 s = (floatx4)0.f;
        const unsigned short* krow = &QKb[(size_t)(b * 4096 + kg) * 128 + 64];
        const short8 kb0 = *(const short8*)&krow[quad * 8];
        const short8 kb1 = *(const short8*)&krow[32 + quad * 8];
        s = __builtin_amdgcn_mfma_f32_16x16x32_bf16(qa0, kb0, s, 0, 0, 0);
        s = __builtin_amdgcn_mfma_f32_16x16x32_bf16(qa1, kb1, s, 0, 0, 0);
        const bool pk = maskx[b * 4096 + kg] < -1e30f;
        unsigned short pbits[4];
#pragma unroll
        for (int r = 0; r < 4; r++) {
            const int qrow = q0 + rb * 16 + quad * 4 + r;
            float p = 0.f;
            if (kg <= qrow && pk == pq[r]) p = __expf(s[r] * scale);
            lacc[r] += p;
            pbits[r] = f2bf(p);
        }
        __syncthreads();
#pragma unroll
        for (int r = 0; r < 4; r++)
            Ps[(rb * 16 + quad * 4 + r) * 40 + kb * 16 + l16] = pbits[r];
        __syncthreads();
        short8 pa[4];
#pragma unroll
        for (int r2 = 0; r2 < 4; r2++)
            pa[r2] = *(const short8*)&Ps[(r2 * 16 + l16) * 40 + quad * 8];
#pragma unroll
        for (int cb = 0; cb < 4; cb++) {
            const short8 vb = *(const short8*)&Vt[(size_t)(dv0 + cb * 16 + l16) * 16384
                                                 + b * 4096 + k0 + quad * 8];
#pragma unroll
            for (int r2 = 0; r2 < 4; r2++)
                acc[r2][cb] = __builtin_amdgcn_mfma_f32_16x16x32_bf16(pa[r2], vb, acc[r2][cb], 0, 0, 0);
        }
    }

#pragma unroll
    for (int r = 0; r < 4; r++) {
        float v = lacc[r];
        v += __shfl_xor(v, 1);
        v += __shfl_xor(v, 2);
        v += __shfl_xor(v, 4);
        v += __shfl_xor(v, 8);
        if (l16 == 0) atomicAdd(&Ls[rb * 16 + quad * 4 + r], v);
    }
    __syncthreads();

#pragma unroll
    for (int r2 = 0; r2 < 4; r2++) {
#pragma unroll
        for (int r = 0; r < 4; r++) {
            const int qrow = q0 + r2 * 16 + quad * 4 + r;
            const float inv = 1.f / Ls[r2 * 16 + quad * 4 + r];
#pragma unroll
            for (int cb = 0; cb < 4; cb++)
                out[(size_t)(b * 4096 + qrow) * 1024 + dv0 + cb * 16 + l16] = acc[r2][cb][r] * inv;
        }
    }
}

extern "C" void kernel_launch(void* const* d_in, const int* in_sizes, int n_in,
                              void* d_out, int out_size, void* d_ws, size_t ws_size,
                              hipStream_t stream) {
    const float* x  = (const float*)d_in[0];
    const float* Wq = (const float*)d_in[1];
    const float* bq = (const float*)d_in[2];
    const float* Wk = (const float*)d_in[3];
    const float* bk = (const float*)d_in[4];
    const float* Wv = (const float*)d_in[5];
    const float* bv = (const float*)d_in[6];
    const float* mk = (const float*)d_in[7];
    float* out = (float*)d_out;

    const int M = 4 * 4096;  // 16384
    char* ws = (char*)d_ws;
    unsigned short* Xb   = (unsigned short*)ws;                      // 32 MB
    unsigned short* Vt   = (unsigned short*)(ws + (33554432));       // 32 MB (1024 x 16384)
    unsigned short* Wvt  = (unsigned short*)(ws + (67108864));       // 2 MB  (1024 x 1024)
    unsigned short* Wqkt = (unsigned short*)(ws + (69206016));       // 256 KB (128 x 1024)
    unsigned short* QKb  = (unsigned short*)(ws + (69468160));       // 4 MB  (16384 x 128)
    float*          bqk  = (float*)(ws + (73662464));                // 512 B

    conv_x<<<2048, 256, 0, stream>>>(x, Xb);
    transpose_w<<<dim3(16, 16), 256, 0, stream>>>(Wv, Wvt, 1024);
    transpose_w<<<dim3(16, 1), 256, 0, stream>>>(Wq, Wqkt, 64);
    transpose_w<<<dim3(16, 1), 256, 0, stream>>>(Wk, Wqkt + 64 * 1024, 64);
    pack_bias<<<1, 128, 0, stream>>>(bq, bk, bqk);

    gemm_bf16<true ><<<dim3(128, 8), 256, 0, stream>>>(Xb, Wvt, bv, Vt, M, 1024);
    gemm_bf16<false><<<dim3(128, 1), 256, 0, stream>>>(Xb, Wqkt, bqk, QKb, M, 128);

    attn_fused<<<dim3(4 * 64 * 2), 512, 0, stream>>>(QKb, Vt, mk, out);
}

// Round 3
// 469.996 us; speedup vs baseline: 1.5918x; 1.0170x over previous
//
#include <hip/hip_runtime.h>
#include <stdint.h>

typedef __attribute__((ext_vector_type(8))) short short8;
typedef __attribute__((ext_vector_type(4))) float floatx4;

__device__ __forceinline__ unsigned short f2bf(float f) {
    unsigned u = __float_as_uint(f);
    u += 0x7FFFu + ((u >> 16) & 1u);
    return (unsigned short)(u >> 16);
}

__device__ __forceinline__ void gload_lds16(const void* g, void* l) {
    __builtin_amdgcn_global_load_lds(
        (const __attribute__((address_space(1))) unsigned int*)g,
        (__attribute__((address_space(3))) unsigned int*)l, 16, 0, 0);
}

// ---- prep: X fp32 -> bf16 (same layout) ----
__global__ __launch_bounds__(256)
void conv_x(const float* __restrict__ x, unsigned short* __restrict__ xb) {
    const size_t total = (size_t)16384 * 1024;
    for (size_t i = ((size_t)blockIdx.x * 256 + threadIdx.x) * 8; i < total;
         i += (size_t)2048 * 256 * 8) {
        float4 a = *(const float4*)&x[i];
        float4 b = *(const float4*)&x[i + 4];
        uint4 o;
        o.x = f2bf(a.x) | ((unsigned)f2bf(a.y) << 16);
        o.y = f2bf(a.z) | ((unsigned)f2bf(a.w) << 16);
        o.z = f2bf(b.x) | ((unsigned)f2bf(b.y) << 16);
        o.w = f2bf(b.z) | ((unsigned)f2bf(b.w) << 16);
        *(uint4*)&xb[i] = o;
    }
}

// ---- prep: W [1024][N] fp32 -> Wt [N][1024] bf16 (LDS-tiled transpose) ----
__global__ __launch_bounds__(256)
void transpose_w(const float* __restrict__ src, unsigned short* __restrict__ dst, int N) {
    __shared__ float T[64][65];
    const int t = threadIdx.x;
    const int k0 = blockIdx.x * 64, n0 = blockIdx.y * 64;
    const int r = t >> 4, c4 = (t & 15) * 4;
#pragma unroll
    for (int i = 0; i < 4; i++) {
        float4 v = *(const float4*)&src[(size_t)(k0 + r + 16 * i) * N + n0 + c4];
        T[r + 16 * i][c4] = v.x; T[r + 16 * i][c4 + 1] = v.y;
        T[r + 16 * i][c4 + 2] = v.z; T[r + 16 * i][c4 + 3] = v.w;
    }
    __syncthreads();
#pragma unroll
    for (int i = 0; i < 4; i++) {
        const int n = n0 + r + 16 * i;
        unsigned short b0 = f2bf(T[c4 + 0][r + 16 * i]);
        unsigned short b1 = f2bf(T[c4 + 1][r + 16 * i]);
        unsigned short b2 = f2bf(T[c4 + 2][r + 16 * i]);
        unsigned short b3 = f2bf(T[c4 + 3][r + 16 * i]);
        uint2 pv;
        pv.x = b0 | ((unsigned)b1 << 16);
        pv.y = b2 | ((unsigned)b3 << 16);
        *(uint2*)&dst[(size_t)n * 1024 + k0 + c4] = pv;
    }
}

__global__ __launch_bounds__(128)
void pack_bias(const float* __restrict__ bq, const float* __restrict__ bk,
               float* __restrict__ bqk) {
    const int t = threadIdx.x;
    bqk[t] = (t < 64) ? bq[t] : bk[t - 64];
}

// ---- m97-style 128x128 bf16 GEMM: C = A[M][1024] @ Bt[N][1024]^T + bias ----
template<bool TRS>
__global__ __launch_bounds__(256)
void gemm_bf16(const unsigned short* __restrict__ A,
               const unsigned short* __restrict__ Bt,
               const float* __restrict__ bias,
               unsigned short* __restrict__ out, int M, int N)
{
    __shared__ unsigned short As[128 * 32];
    __shared__ unsigned short Bs[128 * 32];
    const int tid = threadIdx.x;
    const int w = tid >> 6, l = tid & 63;
    const int quad = l >> 4, l16 = l & 15;
    const int wr = w >> 1, wc = w & 1;
    const int m0 = blockIdx.x * 128, n0 = blockIdx.y * 128;

    const int lr = l >> 2, lk = (l & 3) * 8;
    const unsigned short* Ag0 = A + (size_t)(m0 + w * 16 + lr) * 1024 + lk;
    const unsigned short* Ag1 = Ag0 + (size_t)64 * 1024;
    const unsigned short* Bg0 = Bt + (size_t)(n0 + w * 16 + lr) * 1024 + lk;
    const unsigned short* Bg1 = Bg0 + (size_t)64 * 1024;
    unsigned short* Al0 = &As[w * 512 + l * 8];
    unsigned short* Bl0 = &Bs[w * 512 + l * 8];

    floatx4 acc[4][4];
#pragma unroll
    for (int i = 0; i < 4; i++)
#pragma unroll
        for (int j = 0; j < 4; j++) acc[i][j] = (floatx4)0.f;

    for (int e0 = 0; e0 < 1024; e0 += 32) {
        gload_lds16(Ag0 + e0, Al0);
        gload_lds16(Ag1 + e0, Al0 + 2048);
        gload_lds16(Bg0 + e0, Bl0);
        gload_lds16(Bg1 + e0, Bl0 + 2048);
        __syncthreads();
        short8 af[4], bf[4];
#pragma unroll
        for (int i = 0; i < 4; i++)
            af[i] = *(const short8*)&As[(wr * 64 + i * 16 + l16) * 32 + quad * 8];
#pragma unroll
        for (int j = 0; j < 4; j++)
            bf[j] = *(const short8*)&Bs[(wc * 64 + j * 16 + l16) * 32 + quad * 8];
#pragma unroll
        for (int i = 0; i < 4; i++)
#pragma unroll
            for (int j = 0; j < 4; j++)
                acc[i][j] = __builtin_amdgcn_mfma_f32_16x16x32_bf16(af[i], bf[j], acc[i][j], 0, 0, 0);
        __syncthreads();
    }

#pragma unroll
    for (int j = 0; j < 4; j++) {
        const int n = n0 + wc * 64 + j * 16 + l16;
        const float bn = bias[n];
#pragma unroll
        for (int i = 0; i < 4; i++) {
            const int mb = m0 + wr * 64 + i * 16 + quad * 4;
            if (TRS) {
                unsigned short t[4];
#pragma unroll
                for (int r = 0; r < 4; r++) t[r] = f2bf(acc[i][j][r] + bn);
                uint2 pv;
                pv.x = t[0] | ((unsigned)t[1] << 16);
                pv.y = t[2] | ((unsigned)t[3] << 16);
                *(uint2*)&out[(size_t)n * M + mb] = pv;
            } else {
#pragma unroll
                for (int r = 0; r < 4; r++)
                    out[(size_t)(mb + r) * N + n] = f2bf(acc[i][j][r] + bn);
            }
        }
    }
}

// ---- attention v3: balanced pairing, XCD-local V, pipelined loads, 1 barrier/iter
__global__ __launch_bounds__(512, 4)
void attn_fused(const unsigned short* __restrict__ QKb, // 16384 x 128 bf16 (Q|K)
                const unsigned short* __restrict__ Vt,  // 1024 x 16384 bf16 (dv, bs)
                const float* __restrict__ maskx,        // 4 x 4096
                float* __restrict__ out)                // 4 x 4096 x 1024
{
    __shared__ unsigned short Qs[64 * 72];
    __shared__ unsigned short Ps[2][64 * 40];
    __shared__ float Ls[64];

    const int tid = threadIdx.x;
    const int wave = tid >> 6, lane = tid & 63;
    const int quad = lane >> 4, l16 = lane & 15;
    const int bid = blockIdx.x;
    // bid&7 = (b,dvh): same combo -> same XCD slot under round-robin dispatch
    const int dvh = bid & 1;
    const int b = (bid >> 1) & 3;
    const int t = bid >> 3;                 // 0..63
    const int qt = (t < 32) ? (63 - t) : (t - 32);  // pair sums to 63 per CU
    const int q0 = qt * 64;
    const int gq0 = b * 4096 + q0;

    if (tid < 64) Ls[tid] = 0.f;
    {
        const int r = tid >> 3, c = (tid & 7) * 8;
        uint4 v = *(const uint4*)&QKb[(size_t)(gq0 + r) * 128 + c];
        *(uint4*)&Qs[r * 72 + c] = v;
    }
    __syncthreads();

    const int rb = wave >> 1;   // S-phase row block 0..3
    const int kb = wave & 1;    // S-phase key sub-block 0..1
    bool pq[4];
#pragma unroll
    for (int r = 0; r < 4; r++)
        pq[r] = maskx[b * 4096 + q0 + rb * 16 + quad * 4 + r] < -1e30f;

    const short8 qa0 = *(const short8*)&Qs[(rb * 16 + l16) * 72 + quad * 8];
    const short8 qa1 = *(const short8*)&Qs[(rb * 16 + l16) * 72 + 32 + quad * 8];

    floatx4 acc[4][4];
#pragma unroll
    for (int i = 0; i < 4; i++)
#pragma unroll
        for (int j = 0; j < 4; j++) acc[i][j] = (floatx4)0.f;
    float lacc[4] = {0.f, 0.f, 0.f, 0.f};

    const int niter = 2 * qt + 2;
    const float scale = 0.125f;
    const int dv0 = dvh * 512 + wave * 64;

    // per-lane bases
    const unsigned short* kptr = QKb + ((size_t)(b * 4096 + kb * 16 + l16) * 128 + 64 + quad * 8);
    const float* mptr = maskx + b * 4096 + kb * 16 + l16;
    size_t voff[4];
#pragma unroll
    for (int cb = 0; cb < 4; cb++)
        voff[cb] = (size_t)(dv0 + cb * 16 + l16) * 16384 + b * 4096 + quad * 8;

    // K prefetch for iter 0
    short8 kc0 = *(const short8*)kptr;
    short8 kc1 = *(const short8*)(kptr + 32);

    for (int kt = 0; kt < niter; kt++) {
        const int k0 = kt * 32;
        // V loads for THIS iter issued first (consumed ~after barrier)
        short8 vb[4];
#pragma unroll
        for (int cb = 0; cb < 4; cb++)
            vb[cb] = *(const short8*)&Vt[voff[cb] + k0];
        // S = Q K^T using prefetched K
        floatx4 s = (floatx4)0.f;
        s = __builtin_amdgcn_mfma_f32_16x16x32_bf16(qa0, kc0, s, 0, 0, 0);
        s = __builtin_amdgcn_mfma_f32_16x16x32_bf16(qa1, kc1, s, 0, 0, 0);
        // prefetch K for next iter (clamped to stay in-bounds)
        {
            int kn = k0 + 32 + kb * 16 + l16;
            if (kn > 4095) kn = 4095;
            const unsigned short* np = QKb + ((size_t)(b * 4096 + kn) * 128 + 64 + quad * 8);
            kc0 = *(const short8*)np;
            kc1 = *(const short8*)(np + 32);
        }
        const int kg = k0 + kb * 16 + l16;
        const bool pk = mptr[k0] < -1e30f;
        unsigned short pbits[4];
#pragma unroll
        for (int r = 0; r < 4; r++) {
            const int qrow = q0 + rb * 16 + quad * 4 + r;
            float p = 0.f;
            if (kg <= qrow && pk == pq[r]) p = __expf(s[r] * scale);
            lacc[r] += p;
            pbits[r] = f2bf(p);
        }
        // write P (double-buffered) then single barrier
        unsigned short* Pw = Ps[kt & 1];
#pragma unroll
        for (int r = 0; r < 4; r++)
            Pw[(rb * 16 + quad * 4 + r) * 40 + kb * 16 + l16] = pbits[r];
        __syncthreads();
        const unsigned short* Pr = Ps[kt & 1];
        short8 pa[4];
#pragma unroll
        for (int r2 = 0; r2 < 4; r2++)
            pa[r2] = *(const short8*)&Pr[(r2 * 16 + l16) * 40 + quad * 8];
#pragma unroll
        for (int cb = 0; cb < 4; cb++)
#pragma unroll
            for (int r2 = 0; r2 < 4; r2++)
                acc[r2][cb] = __builtin_amdgcn_mfma_f32_16x16x32_bf16(pa[r2], vb[cb], acc[r2][cb], 0, 0, 0);
    }

#pragma unroll
    for (int r = 0; r < 4; r++) {
        float v = lacc[r];
        v += __shfl_xor(v, 1);
        v += __shfl_xor(v, 2);
        v += __shfl_xor(v, 4);
        v += __shfl_xor(v, 8);
        if (l16 == 0) atomicAdd(&Ls[rb * 16 + quad * 4 + r], v);
    }
    __syncthreads();

#pragma unroll
    for (int r2 = 0; r2 < 4; r2++) {
#pragma unroll
        for (int r = 0; r < 4; r++) {
            const int qrow = q0 + r2 * 16 + quad * 4 + r;
            const float inv = 1.f / Ls[r2 * 16 + quad * 4 + r];
#pragma unroll
            for (int cb = 0; cb < 4; cb++)
                out[(size_t)(b * 4096 + qrow) * 1024 + dv0 + cb * 16 + l16] = acc[r2][cb][r] * inv;
        }
    }
}

extern "C" void kernel_launch(void* const* d_in, const int* in_sizes, int n_in,
                              void* d_out, int out_size, void* d_ws, size_t ws_size,
                              hipStream_t stream) {
    const float* x  = (const float*)d_in[0];
    const float* Wq = (const float*)d_in[1];
    const float* bq = (const float*)d_in[2];
    const float* Wk = (const float*)d_in[3];
    const float* bk = (const float*)d_in[4];
    const float* Wv = (const float*)d_in[5];
    const float* bv = (const float*)d_in[6];
    const float* mk = (const float*)d_in[7];
    float* out = (float*)d_out;

    const int M = 4 * 4096;  // 16384
    char* ws = (char*)d_ws;
    unsigned short* Xb   = (unsigned short*)ws;                      // 32 MB
    unsigned short* Vt   = (unsigned short*)(ws + (33554432));       // 32 MB (1024 x 16384)
    unsigned short* Wvt  = (unsigned short*)(ws + (67108864));       // 2 MB  (1024 x 1024)
    unsigned short* Wqkt = (unsigned short*)(ws + (69206016));       // 256 KB (128 x 1024)
    unsigned short* QKb  = (unsigned short*)(ws + (69468160));       // 4 MB  (16384 x 128)
    float*          bqk  = (float*)(ws + (73662464));                // 512 B

    conv_x<<<2048, 256, 0, stream>>>(x, Xb);
    transpose_w<<<dim3(16, 16), 256, 0, stream>>>(Wv, Wvt, 1024);
    transpose_w<<<dim3(16, 1), 256, 0, stream>>>(Wq, Wqkt, 64);
    transpose_w<<<dim3(16, 1), 256, 0, stream>>>(Wk, Wqkt + 64 * 1024, 64);
    pack_bias<<<1, 128, 0, stream>>>(bq, bk, bqk);

    gemm_bf16<true ><<<dim3(128, 8), 256, 0, stream>>>(Xb, Wvt, bv, Vt, M, 1024);
    gemm_bf16<false><<<dim3(128, 1), 256, 0, stream>>>(Xb, Wqkt, bqk, QKb, M, 128);

    attn_fused<<<dim3(4 * 64 * 2), 512, 0, stream>>>(QKb, Vt, mk, out);
}